// Round 3
// baseline (427.554 us; speedup 1.0000x reference)
//
#include <hip/hip_runtime.h>
#include <hip/hip_bf16.h>
#include <stdint.h>

// B=16, K=8, N=196, D=768, H=3072, DOUT=768
// y[b,n,:] = (mean_k relu(slots[b,k]@W1 + pos[n]@W1 + b1)) @ W2 + b2
// (softmax over K of K-identical values is exactly 1/K; map_alpha unused)
//
// FUSED single-dispatch, liveness-hardened: 512 blocks x 256 thr, 48 KB LDS,
// __launch_bounds__(256,2) -> 2 blocks/CU needs 96/160 KB LDS, 8/32 waves,
// VGPR<=256: co-residency of all 512 blocks holds with ~2x margin on every
// resource (R2 lesson: 3/CU at 144/160 KB LDS deadlocked the container).
// Phases (verbatim bodies from the verified 129us 4-dispatch version, only
// grid-stride wrappers over 512 blocks):
//   P1 prep:   W1->W1t atoms + A1=[slots;pos] atoms (flat grid-stride)
//   P2 gemm1:  blocks 0..287 C1 = A1 @ W1t^T (XCD nt-swizzle);
//              blocks 288..511 W2->W2t (strided loop)
//   P3 hbar:   Hb atoms (4704 virtual blocks, stride 512)
//   P4 gemm2:  out = Hb @ W2t^T + b2 (588 tiles, stride 512; 4 waves 2x2
//              of 32x32, 48-atom K loop)
// Grid barrier: ticket-counter on zero-init __device__ globals (no memset,
// replay-safe: each launch adds exactly NBLK -> counter stays ==0 mod NBLK),
// atomicAdd (device-scope, m20) + AGENT-scope spin + __threadfence both
// sides (cross-XCD L2 writeback/invalidate, Guideline 16). Spin bounded
// (~16ms) so a residency bug yields wrong-results, never a GPU hang.
// Atom = 64x64 bf16 tile, image [kb 0..7][r 0..63] chunks of 8; off=(kb*64+r)*8.

typedef __attribute__((ext_vector_type(8))) short bf16x8;
typedef __attribute__((ext_vector_type(4))) float f32x4;

#define AS1 __attribute__((address_space(1)))
#define AS3 __attribute__((address_space(3)))

#define WAIT_VM(N) asm volatile("s_waitcnt vmcnt(" #N ")" ::: "memory")
#define BAR()      asm volatile("s_barrier" ::: "memory")
#define BAR_LDS()  asm volatile("s_waitcnt lgkmcnt(0)\ns_barrier" ::: "memory")

#define NBLK 512u

__device__ unsigned int g_bar[3];   // zero-init at module load; ticket barrier

static __device__ __forceinline__ void gld_lds16(const void* g, void* l) {
    __builtin_amdgcn_global_load_lds((const AS1 unsigned int*)g,
                                     (AS3 unsigned int*)l, 16, 0, 0);
}

static __device__ __forceinline__ unsigned short f2bf(float f) {
    union { float f; unsigned int u; } v; v.f = f;
    unsigned int u = v.u;
    return (unsigned short)((u + 0x7fffu + ((u >> 16) & 1u)) >> 16);  // RNE
}

// device-scope grid barrier (ticket): all NBLK blocks arrive, then proceed.
static __device__ __forceinline__ void grid_barrier(int i) {
    __threadfence();
    __syncthreads();
    if (threadIdx.x == 0) {
        unsigned int old = atomicAdd(&g_bar[i], 1u);
        unsigned int target = (old / NBLK + 1u) * NBLK;
        int guard = 0;
        while (__hip_atomic_load(&g_bar[i], __ATOMIC_RELAXED,
                                 __HIP_MEMORY_SCOPE_AGENT) < target) {
            __builtin_amdgcn_s_sleep(8);
            if (++guard > (1 << 17)) break;   // escape hatch: never hang the GPU
        }
    }
    __syncthreads();
    __threadfence();
}

__launch_bounds__(256, 2)
__global__ void k_fused(const float* __restrict__ S, const float* __restrict__ P,
                        const float* __restrict__ W1, const float* __restrict__ b1,
                        const float* __restrict__ W2, const float* __restrict__ b2,
                        unsigned short* __restrict__ W1t, unsigned short* __restrict__ W2t,
                        unsigned short* __restrict__ A1, float* __restrict__ C1,
                        unsigned short* __restrict__ Hb, float* __restrict__ out) {
    __shared__ unsigned short sm[3 * 8192];   // 48 KB (P2 gemm1 + P4 gemm2)

    const int tid  = threadIdx.x;
    const int bid  = blockIdx.x;
    const int lane = tid & 63;
    const int wave = tid >> 6;
    const int q = lane >> 4, l16 = lane & 15;

    // ---------------- P1: prep (W1t tiled transpose + A1 tiled pack) ----------------
    {
        const int C1n = 96 * 3072;          // W1t tasks
        const int TOT = C1n + 96 * 384;     // + A1 tasks = 331776
        for (int idx = bid * 256 + tid; idx < TOT; idx += 512 * 256) {
            if (idx < C1n) {
                int r  = idx % 3072;        // consecutive tid -> consecutive r (coalesced)
                int kc = idx / 3072;        // 8-elem k-chunk (0..95)
                unsigned int po[4];
                #pragma unroll
                for (int j = 0; j < 4; ++j) {
                    unsigned short lo = f2bf(W1[(size_t)(kc * 8 + 2 * j) * 3072 + r]);
                    unsigned short hi = f2bf(W1[(size_t)(kc * 8 + 2 * j + 1) * 3072 + r]);
                    po[j] = (unsigned int)lo | ((unsigned int)hi << 16);
                }
                size_t dst = ((size_t)(r >> 6) * 12 + (kc >> 3)) * 4096
                           + (size_t)((kc & 7) * 64 + (r & 63)) * 8;
                *(uint4*)(W1t + dst) = make_uint4(po[0], po[1], po[2], po[3]);
            } else {
                int t = idx - C1n;
                int r  = t % 384;
                int kc = t / 384;
                uint4 o = make_uint4(0u, 0u, 0u, 0u);
                if (r < 324) {
                    const float* src = (r < 128) ? (S + (size_t)r * 768 + kc * 8)
                                                 : (P + (size_t)(r - 128) * 768 + kc * 8);
                    float4 a = *(const float4*)(src);
                    float4 b = *(const float4*)(src + 4);
                    o.x = (unsigned int)f2bf(a.x) | ((unsigned int)f2bf(a.y) << 16);
                    o.y = (unsigned int)f2bf(a.z) | ((unsigned int)f2bf(a.w) << 16);
                    o.z = (unsigned int)f2bf(b.x) | ((unsigned int)f2bf(b.y) << 16);
                    o.w = (unsigned int)f2bf(b.z) | ((unsigned int)f2bf(b.w) << 16);
                }
                size_t dst = ((size_t)(r >> 6) * 12 + (kc >> 3)) * 4096
                           + (size_t)((kc & 7) * 64 + (r & 63)) * 8;
                *(uint4*)(A1 + dst) = o;
            }
        }
    }
    grid_barrier(0);

    // ---------------- P2: GEMM1 (blocks 0..287) + W2t (blocks 288..511) ----------------
    if (bid < 288) {
        const int wm = wave >> 1, wn = wave & 1;
        // swizzle: XCD x = bid&7 owns nt in [6x, 6x+6) -> W1t slice L2-resident
        const int j  = bid >> 3;
        const int nt = (bid & 7) * 6 + j % 6;
        const int rt = j / 6;

        const unsigned short* Ab = A1  + (size_t)rt * 12 * 4096;
        const unsigned short* Bb = W1t + (size_t)nt * 12 * 4096;

        f32x4 acc[2][2] = {};
        const int offA = (wm * 32 + l16) * 8;
        const int offB = 4096 + (wn * 32 + l16) * 8;

        auto stage = [&](int i, unsigned short* d) {     // 4 loads/thread
            const unsigned short* Ag = Ab + (size_t)i * 4096;
            const unsigned short* Bg = Bb + (size_t)i * 4096;
            gld_lds16(Ag + tid * 8,        d + tid * 8);
            gld_lds16(Ag + 2048 + tid * 8, d + 2048 + tid * 8);
            gld_lds16(Bg + tid * 8,        d + 4096 + tid * 8);
            gld_lds16(Bg + 2048 + tid * 8, d + 6144 + tid * 8);
        };
        auto compute = [&](const unsigned short* buf) {
            #pragma unroll
            for (int ks = 0; ks < 2; ++ks) {
                const int ko = (ks * 4 + q) * 512;
                bf16x8 af0 = *(const bf16x8*)(buf + ko + offA);
                bf16x8 af1 = *(const bf16x8*)(buf + ko + offA + 128);
                bf16x8 bf0 = *(const bf16x8*)(buf + ko + offB);
                bf16x8 bf1 = *(const bf16x8*)(buf + ko + offB + 128);
                acc[0][0] = __builtin_amdgcn_mfma_f32_16x16x32_bf16(af0, bf0, acc[0][0], 0, 0, 0);
                acc[0][1] = __builtin_amdgcn_mfma_f32_16x16x32_bf16(af0, bf1, acc[0][1], 0, 0, 0);
                acc[1][0] = __builtin_amdgcn_mfma_f32_16x16x32_bf16(af1, bf0, acc[1][0], 0, 0, 0);
                acc[1][1] = __builtin_amdgcn_mfma_f32_16x16x32_bf16(af1, bf1, acc[1][1], 0, 0, 0);
            }
        };

        unsigned short* s0 = sm;
        unsigned short* s1 = sm + 8192;
        unsigned short* s2 = sm + 16384;

        stage(0, s0);
        stage(1, s1);
        for (int i = 0; i < 12; i += 3) {
            stage(i + 2, s2); WAIT_VM(8);
            BAR(); compute(s0); BAR_LDS();
            if (i + 3 < 12) { stage(i + 3, s0); WAIT_VM(8); } else { WAIT_VM(4); }
            BAR(); compute(s1); BAR_LDS();
            if (i + 4 < 12) { stage(i + 4, s1); WAIT_VM(8); }
            else if (i + 3 < 12) { WAIT_VM(4); }
            else { WAIT_VM(0); }
            BAR(); compute(s2);
            if (i + 3 < 12) BAR_LDS();
        }

        const int row0 = rt * 64 + wm * 32;
        const int col0 = nt * 64 + wn * 32;
        #pragma unroll
        for (int ii = 0; ii < 2; ++ii) {
            #pragma unroll
            for (int jj = 0; jj < 2; ++jj) {
                int col = col0 + jj * 16 + l16;
                #pragma unroll
                for (int r = 0; r < 4; ++r) {
                    int row = row0 + ii * 16 + q * 4 + r;
                    if (row < 324) C1[(size_t)row * 3072 + col] = acc[ii][jj][r];
                }
            }
        }
    } else {
        // ---- W2t conversion: 294912 uint4-tasks over 224 blocks, strided ----
        int base = (bid - 288) * 256 + tid;          // 0..57343
        for (int idx = base; idx < 294912; idx += 224 * 256) {
            int r  = idx % 768;
            int kc = idx / 768;         // 0..383
            unsigned int po[4];
            #pragma unroll
            for (int j = 0; j < 4; ++j) {
                unsigned short lo = f2bf(W2[(size_t)(kc * 8 + 2 * j) * 768 + r]);
                unsigned short hi = f2bf(W2[(size_t)(kc * 8 + 2 * j + 1) * 768 + r]);
                po[j] = (unsigned int)lo | ((unsigned int)hi << 16);
            }
            size_t dst = ((size_t)(r >> 6) * 48 + (kc >> 3)) * 4096
                       + (size_t)((kc & 7) * 64 + (r & 63)) * 8;
            *(uint4*)(W2t + dst) = make_uint4(po[0], po[1], po[2], po[3]);
        }
    }
    grid_barrier(1);

    // ---------------- P3: hbar (Hb atoms, 4704 virtual blocks, stride 512) ----------------
    #pragma unroll 1
    for (int vb = bid; vb < 4704; vb += 512) {
        const int bx   = vb % 49;                      // row-atom 0..48
        const int yq   = vb / 49;                      // 0..95
        const int hc   = yq * 4 + wave;                // 0..383
        const int h0   = hc * 8;
        const int bn   = bx * 64 + lane;               // 0..3135 (49*64=3136 exact)
        const int b    = bn / 196;
        const int n    = bn - b * 196;
        const float* prow = C1 + (size_t)(128 + n) * 3072 + h0;
        float4 pA = *(const float4*)(prow);
        float4 pB = *(const float4*)(prow + 4);
        float4 bA = *(const float4*)(b1 + h0);
        float4 bB = *(const float4*)(b1 + h0 + 4);
        float pb[8] = { pA.x + bA.x, pA.y + bA.y, pA.z + bA.z, pA.w + bA.w,
                        pB.x + bB.x, pB.y + bB.y, pB.z + bB.z, pB.w + bB.w };
        float acc[8] = {};
        #pragma unroll
        for (int k = 0; k < 8; ++k) {
            const float* srow = C1 + (size_t)(b * 8 + k) * 3072 + h0;  // wave-broadcast-ish
            float4 sA_ = *(const float4*)(srow);
            float4 sB_ = *(const float4*)(srow + 4);
            acc[0] += fmaxf(sA_.x + pb[0], 0.f);
            acc[1] += fmaxf(sA_.y + pb[1], 0.f);
            acc[2] += fmaxf(sA_.z + pb[2], 0.f);
            acc[3] += fmaxf(sA_.w + pb[3], 0.f);
            acc[4] += fmaxf(sB_.x + pb[4], 0.f);
            acc[5] += fmaxf(sB_.y + pb[5], 0.f);
            acc[6] += fmaxf(sB_.z + pb[6], 0.f);
            acc[7] += fmaxf(sB_.w + pb[7], 0.f);
        }
        unsigned int w0 = (unsigned int)f2bf(acc[0] * 0.125f) | ((unsigned int)f2bf(acc[1] * 0.125f) << 16);
        unsigned int w1 = (unsigned int)f2bf(acc[2] * 0.125f) | ((unsigned int)f2bf(acc[3] * 0.125f) << 16);
        unsigned int w2 = (unsigned int)f2bf(acc[4] * 0.125f) | ((unsigned int)f2bf(acc[5] * 0.125f) << 16);
        unsigned int w3 = (unsigned int)f2bf(acc[6] * 0.125f) | ((unsigned int)f2bf(acc[7] * 0.125f) << 16);
        size_t dst = ((size_t)bx * 48 + (hc >> 3)) * 4096
                   + (size_t)((hc & 7) * 64 + lane) * 8;
        *(uint4*)(Hb + dst) = make_uint4(w0, w1, w2, w3);
    }
    grid_barrier(2);

    // ---------------- P4: GEMM2 (588 tiles, stride 512; 4 waves 2x2 of 32x32) ----------------
    #pragma unroll 1
    for (int t4 = bid; t4 < 588; t4 += 512) {
        __syncthreads();                        // LDS reuse across tiles
        const int wm = wave >> 1, wn = wave & 1;
        int rt, nt;
        if (t4 < 576) { rt = (t4 & 7) + 8 * ((t4 >> 3) % 6); nt = (t4 >> 3) / 6; }
        else          { rt = 48; nt = t4 - 576; }

        const unsigned short* Ab = Hb  + (size_t)rt * 48 * 4096;
        const unsigned short* Bb = W2t + (size_t)nt * 48 * 4096;

        f32x4 acc[2][2] = {};
        const int offA = (wm * 32 + l16) * 8;
        const int offB = 4096 + (wn * 32 + l16) * 8;

        auto stage = [&](int i, unsigned short* d) {     // 4 loads/thread
            const unsigned short* Ag = Ab + (size_t)i * 4096;
            const unsigned short* Bg = Bb + (size_t)i * 4096;
            gld_lds16(Ag + tid * 8,        d + tid * 8);
            gld_lds16(Ag + 2048 + tid * 8, d + 2048 + tid * 8);
            gld_lds16(Bg + tid * 8,        d + 4096 + tid * 8);
            gld_lds16(Bg + 2048 + tid * 8, d + 6144 + tid * 8);
        };
        auto compute = [&](const unsigned short* buf) {
            #pragma unroll
            for (int ks = 0; ks < 2; ++ks) {
                const int ko = (ks * 4 + q) * 512;
                bf16x8 af0 = *(const bf16x8*)(buf + ko + offA);
                bf16x8 af1 = *(const bf16x8*)(buf + ko + offA + 128);
                bf16x8 bf0 = *(const bf16x8*)(buf + ko + offB);
                bf16x8 bf1 = *(const bf16x8*)(buf + ko + offB + 128);
                acc[0][0] = __builtin_amdgcn_mfma_f32_16x16x32_bf16(af0, bf0, acc[0][0], 0, 0, 0);
                acc[0][1] = __builtin_amdgcn_mfma_f32_16x16x32_bf16(af0, bf1, acc[0][1], 0, 0, 0);
                acc[1][0] = __builtin_amdgcn_mfma_f32_16x16x32_bf16(af1, bf0, acc[1][0], 0, 0, 0);
                acc[1][1] = __builtin_amdgcn_mfma_f32_16x16x32_bf16(af1, bf1, acc[1][1], 0, 0, 0);
            }
        };

        unsigned short* s0 = sm;
        unsigned short* s1 = sm + 8192;
        unsigned short* s2 = sm + 16384;

        stage(0, s0);
        stage(1, s1);
        for (int i = 0; i < 48; i += 3) {
            stage(i + 2, s2); WAIT_VM(8);
            BAR(); compute(s0); BAR_LDS();
            if (i + 3 < 48) { stage(i + 3, s0); WAIT_VM(8); } else { WAIT_VM(4); }
            BAR(); compute(s1); BAR_LDS();
            if (i + 4 < 48) { stage(i + 4, s1); WAIT_VM(8); }
            else if (i + 3 < 48) { WAIT_VM(4); }
            else { WAIT_VM(0); }
            BAR(); compute(s2);
            if (i + 3 < 48) BAR_LDS();
        }

        // epilogue: C/D col=lane&15, row=(lane>>4)*4+reg; 3136 = 49*64 -> no bounds
        const int row0 = rt * 64 + wm * 32;
        const int col0 = nt * 64 + wn * 32;
        #pragma unroll
        for (int ii = 0; ii < 2; ++ii) {
            #pragma unroll
            for (int jj = 0; jj < 2; ++jj) {
                int col = col0 + jj * 16 + l16;
                float bv = b2[col];
                #pragma unroll
                for (int r = 0; r < 4; ++r) {
                    int row = row0 + ii * 16 + q * 4 + r;
                    out[(size_t)row * 768 + col] = acc[ii][jj][r] + bv;
                }
            }
        }
    }
}

extern "C" void kernel_launch(void* const* d_in, const int* in_sizes, int n_in,
                              void* d_out, int out_size, void* d_ws, size_t ws_size,
                              hipStream_t stream) {
    const float* slots  = (const float*)d_in[0];   // 16*8*768
    const float* pos    = (const float*)d_in[1];   // 196*768
    // d_in[2] = map_alpha: unused (softmax over K of identical values = 1/K)
    const float* W1     = (const float*)d_in[3];   // 768*3072
    const float* b1     = (const float*)d_in[4];   // 3072
    const float* W2     = (const float*)d_in[5];   // 3072*768
    const float* b2     = (const float*)d_in[6];   // 768
    float* out = (float*)d_out;                    // 3136*768 f32

    size_t off = 0;
    auto alloc = [&](size_t bytes) {
        void* p = (char*)d_ws + off;
        off += (bytes + 255) & ~(size_t)255;
        return p;
    };
    unsigned short* W1t = (unsigned short*)alloc((size_t)3072 * 768 * 2);     // [48][12] atoms
    unsigned short* W2t = (unsigned short*)alloc((size_t)768 * 3072 * 2);     // [12][48] atoms
    unsigned short* A1  = (unsigned short*)alloc((size_t)384 * 768 * 2);      // [6][12] atoms
    float*          C1  = (float*)alloc((size_t)384 * 3072 * 4);              // row-major
    unsigned short* Hb  = (unsigned short*)alloc((size_t)49 * 48 * 4096 * 2); // [49][48] atoms

    k_fused<<<512, 256, 0, stream>>>(slots, pos, W1, b1, W2, b2,
                                     W1t, W2t, A1, C1, Hb, out);
}

// Round 4
// 160.863 us; speedup vs baseline: 2.6579x; 2.6579x over previous
//
#include <hip/hip_runtime.h>
#include <hip/hip_bf16.h>
#include <stdint.h>

// B=16, K=8, N=196, D=768, H=3072, DOUT=768
// y[b,n,:] = (mean_k relu(slots[b,k]@W1 + pos[n]@W1 + b1)) @ W2 + b2
// (softmax over K of K-identical values is exactly 1/K; map_alpha unused)
//
// 3-dispatch structure (R3 lesson: grid-wide sync costs ~300us in agent-scope
// cache ops on gfx950 -> persistent fusion abandoned; instead remove the prep
// dispatch by loading gemm1 fragments DIRECTLY from f32 globals):
//  k_gemm1d: blocks 0..287: C1 = [S;P] @ W1 with in-register f32->bf16
//            conversion (v_cvt_pk_bf16_f32, RNE — bit-identical to f2bf path).
//            A-frags: 2xfloat4 per-lane-row + imm offsets (full unroll).
//            B-frags: 8 k-strided dwords, 8 loop-invariant voffsets + uniform
//            SGPR base (saddr form), L2-resident via XCD nt-swizzle.
//            No LDS, no barriers. Blocks 288..575: W2->W2t atoms (4 chunks).
//  k_hbar:   Hb atoms (49 row-atoms, 4704 blocks)           [verbatim champion]
//  k_gemm2:  out = Hb @ W2t^T + b2 (588 blk x 512 thr,
//            K-split-2, wave-tile 32x32, 3-stage)           [verbatim champion]
// Atom = 64x64 bf16 tile, image [kb 0..7][r 0..63] chunks of 8; off=(kb*64+r)*8.

typedef __attribute__((ext_vector_type(8))) short bf16x8;
typedef __attribute__((ext_vector_type(4))) float f32x4;

#define AS1 __attribute__((address_space(1)))
#define AS3 __attribute__((address_space(3)))

#define WAIT_VM(N) asm volatile("s_waitcnt vmcnt(" #N ")" ::: "memory")
#define BAR()      asm volatile("s_barrier" ::: "memory")
#define BAR_LDS()  asm volatile("s_waitcnt lgkmcnt(0)\ns_barrier" ::: "memory")

static __device__ __forceinline__ void gld_lds16(const void* g, void* l) {
    __builtin_amdgcn_global_load_lds((const AS1 unsigned int*)g,
                                     (AS3 unsigned int*)l, 16, 0, 0);
}

static __device__ __forceinline__ unsigned short f2bf(float f) {
    union { float f; unsigned int u; } v; v.f = f;
    unsigned int u = v.u;
    return (unsigned short)((u + 0x7fffu + ((u >> 16) & 1u)) >> 16);  // RNE
}

static __device__ __forceinline__ unsigned int pkbf(float lo, float hi) {
    unsigned int d;                               // RNE, same as f2bf pair
    asm("v_cvt_pk_bf16_f32 %0, %1, %2" : "=v"(d) : "v"(lo), "v"(hi));
    return d;
}

// ---- k_gemm1d: 576 blocks x 256 thr ----
// blocks 0..287: frag-direct GEMM1 (BM=BN=64, 4 waves 2x2 of 32x32)
// blocks 288..575: W2t conversion, 4 strided chunks each
__global__ void k_gemm1d(const float* __restrict__ S, const float* __restrict__ P,
                         const float* __restrict__ W1, const float* __restrict__ W2,
                         float* __restrict__ C1, unsigned short* __restrict__ W2t) {
    const int tid = threadIdx.x;
    const int bid = blockIdx.x;

    if (bid >= 288) {                   // ---- W2t conversion ----
        int base = (bid - 288) * 256 + tid;          // 0..73727
        #pragma unroll 1
        for (int idx = base; idx < 294912; idx += 288 * 256) {  // exactly 4 chunks
            int r  = idx % 768;
            int kc = idx / 768;         // 0..383
            unsigned int po[4];
            #pragma unroll
            for (int j = 0; j < 4; ++j) {
                unsigned short lo = f2bf(W2[(size_t)(kc * 8 + 2 * j) * 768 + r]);
                unsigned short hi = f2bf(W2[(size_t)(kc * 8 + 2 * j + 1) * 768 + r]);
                po[j] = (unsigned int)lo | ((unsigned int)hi << 16);
            }
            size_t dst = ((size_t)(r >> 6) * 48 + (kc >> 3)) * 4096
                       + (size_t)((kc & 7) * 64 + (r & 63)) * 8;
            *(uint4*)(W2t + dst) = make_uint4(po[0], po[1], po[2], po[3]);
        }
        return;
    }

    const int lane = tid & 63;
    const int wave = tid >> 6;
    const int wm = wave >> 1, wn = wave & 1;
    const int q = lane >> 4, l16 = lane & 15;

    // swizzle: XCD x = bid&7 owns nt in [6x, 6x+6) -> W1 col-slice L2-resident
    const int jj_ = bid >> 3;
    const int nt = (bid & 7) * 6 + jj_ % 6;
    const int rt = jj_ / 6;

    // A row pointers; rows >=324 clamped (their C rows are discarded at store)
    auto rowptr = [&](int row) -> const float* {
        row = row < 324 ? row : 323;
        return (row < 128) ? (S + (size_t)row * 768) : (P + (size_t)(row - 128) * 768);
    };
    const float* pA0 = rowptr(rt * 64 + wm * 32 + l16) + q * 8;
    const float* pA1 = rowptr(rt * 64 + wm * 32 + 16 + l16) + q * 8;

    // B: 8 per-lane 32-bit byte voffsets (k-row q*8+j, col nt*64+wn*32+l16);
    // uniform k-base walks (i,ks). bf1 col = +16 via imm (+64 bytes).
    unsigned int boff[8];
    #pragma unroll
    for (int j = 0; j < 8; ++j)
        boff[j] = (unsigned int)((((q * 8 + j) * 3072) + nt * 64 + wn * 32 + l16) * 4);

    f32x4 acc[2][2] = {};
    #pragma unroll
    for (int i = 0; i < 12; ++i) {
        #pragma unroll
        for (int ks = 0; ks < 2; ++ks) {
            const int k0 = i * 64 + ks * 32;        // lane adds q*8 via pointers
            // ---- A loads (contiguous k) ----
            f32x4 a0lo = *(const f32x4*)(pA0 + k0);
            f32x4 a0hi = *(const f32x4*)(pA0 + k0 + 4);
            f32x4 a1lo = *(const f32x4*)(pA1 + k0);
            f32x4 a1hi = *(const f32x4*)(pA1 + k0 + 4);
            // ---- B loads (k-strided dwords, saddr + voffset form) ----
            const char* bb = (const char*)W1 + (size_t)k0 * 3072 * 4;
            float b0[8], b1[8];
            #pragma unroll
            for (int j = 0; j < 8; ++j) {
                b0[j] = *(const float*)(bb + boff[j]);        // col c
                b1[j] = *(const float*)(bb + boff[j] + 64);   // col c+16
            }
            // ---- pack to bf16 (RNE) ----
            union { unsigned int u[4]; bf16x8 v; } af0, af1, bf0, bf1;
            #pragma unroll
            for (int p = 0; p < 2; ++p) {
                af0.u[p]     = pkbf(a0lo[2 * p], a0lo[2 * p + 1]);
                af0.u[p + 2] = pkbf(a0hi[2 * p], a0hi[2 * p + 1]);
                af1.u[p]     = pkbf(a1lo[2 * p], a1lo[2 * p + 1]);
                af1.u[p + 2] = pkbf(a1hi[2 * p], a1hi[2 * p + 1]);
            }
            #pragma unroll
            for (int p = 0; p < 4; ++p) {
                bf0.u[p] = pkbf(b0[2 * p], b0[2 * p + 1]);
                bf1.u[p] = pkbf(b1[2 * p], b1[2 * p + 1]);
            }
            acc[0][0] = __builtin_amdgcn_mfma_f32_16x16x32_bf16(af0.v, bf0.v, acc[0][0], 0, 0, 0);
            acc[0][1] = __builtin_amdgcn_mfma_f32_16x16x32_bf16(af0.v, bf1.v, acc[0][1], 0, 0, 0);
            acc[1][0] = __builtin_amdgcn_mfma_f32_16x16x32_bf16(af1.v, bf0.v, acc[1][0], 0, 0, 0);
            acc[1][1] = __builtin_amdgcn_mfma_f32_16x16x32_bf16(af1.v, bf1.v, acc[1][1], 0, 0, 0);
        }
    }

    // epilogue: C/D col=lane&15, row=(lane>>4)*4+reg
    const int row0 = rt * 64 + wm * 32;
    const int col0 = nt * 64 + wn * 32;
    #pragma unroll
    for (int ii = 0; ii < 2; ++ii) {
        #pragma unroll
        for (int jj = 0; jj < 2; ++jj) {
            int col = col0 + jj * 16 + l16;
            #pragma unroll
            for (int r = 0; r < 4; ++r) {
                int row = row0 + ii * 16 + q * 4 + r;
                if (row < 324) C1[(size_t)row * 3072 + col] = acc[ii][jj][r];
            }
        }
    }
}

// ---- hbar: Hb atoms (49 row-atoms), 4704 blocks ----
__global__ void k_hbar(const float* __restrict__ C1, const float* __restrict__ b1,
                       unsigned short* __restrict__ Hb) {
    const int bid  = blockIdx.x;
    const int tid  = threadIdx.x;
    const int bx   = bid % 49;                     // row-atom 0..48
    const int yq   = bid / 49;                     // 0..95
    const int lane = tid & 63;
    const int wv   = tid >> 6;
    const int hc   = yq * 4 + wv;                  // 0..383
    const int h0   = hc * 8;
    const int bn   = bx * 64 + lane;               // 0..3135 (49*64=3136 exact)
    const int b    = bn / 196;
    const int n    = bn - b * 196;
    const float* prow = C1 + (size_t)(128 + n) * 3072 + h0;
    float4 pA = *(const float4*)(prow);
    float4 pB = *(const float4*)(prow + 4);
    float4 bA = *(const float4*)(b1 + h0);
    float4 bB = *(const float4*)(b1 + h0 + 4);
    float pb[8] = { pA.x + bA.x, pA.y + bA.y, pA.z + bA.z, pA.w + bA.w,
                    pB.x + bB.x, pB.y + bB.y, pB.z + bB.z, pB.w + bB.w };
    float acc[8] = {};
    #pragma unroll
    for (int k = 0; k < 8; ++k) {
        const float* srow = C1 + (size_t)(b * 8 + k) * 3072 + h0;  // wave-broadcast-ish
        float4 sA_ = *(const float4*)(srow);
        float4 sB_ = *(const float4*)(srow + 4);
        acc[0] += fmaxf(sA_.x + pb[0], 0.f);
        acc[1] += fmaxf(sA_.y + pb[1], 0.f);
        acc[2] += fmaxf(sA_.z + pb[2], 0.f);
        acc[3] += fmaxf(sA_.w + pb[3], 0.f);
        acc[4] += fmaxf(sB_.x + pb[4], 0.f);
        acc[5] += fmaxf(sB_.y + pb[5], 0.f);
        acc[6] += fmaxf(sB_.z + pb[6], 0.f);
        acc[7] += fmaxf(sB_.w + pb[7], 0.f);
    }
    unsigned int w0 = (unsigned int)f2bf(acc[0] * 0.125f) | ((unsigned int)f2bf(acc[1] * 0.125f) << 16);
    unsigned int w1 = (unsigned int)f2bf(acc[2] * 0.125f) | ((unsigned int)f2bf(acc[3] * 0.125f) << 16);
    unsigned int w2 = (unsigned int)f2bf(acc[4] * 0.125f) | ((unsigned int)f2bf(acc[5] * 0.125f) << 16);
    unsigned int w3 = (unsigned int)f2bf(acc[6] * 0.125f) | ((unsigned int)f2bf(acc[7] * 0.125f) << 16);
    size_t dst = ((size_t)bx * 48 + (hc >> 3)) * 4096
               + (size_t)((hc & 7) * 64 + lane) * 8;
    *(uint4*)(Hb + dst) = make_uint4(w0, w1, w2, w3);
}

// ---- GEMM2: BM=BN=64, 512 threads, K-split-2: 2 K-groups x 4 waves of 32x32 ----
// 588 blocks (49 rt x 12 nt), rt-XCD partition: rt=(id&7)+8*((id>>3)%6), tail rt=48.
// Hb atoms [49][48][4096]; W2t atoms [12][48][4096]; out 3136x768 f32 + b2.
__launch_bounds__(512)
__global__ void k_gemm2(const unsigned short* __restrict__ Hb,
                        const unsigned short* __restrict__ W2t,
                        const float* __restrict__ b2, float* __restrict__ out) {
    __shared__ unsigned short sm[3 * 8192];    // 48 KB: [stage][A 4096 | B 4096 elems]

    const int tid  = threadIdx.x;              // 0..511
    const int lane = tid & 63;
    const int wave = tid >> 6;                 // 0..7
    const int kg = wave >> 2;                  // K-group 0/1
    const int w  = wave & 3;                   // wave-in-group
    const int wm = w >> 1, wn = w & 1;         // 2 x 2 wave grid, tile 32x32
    const int q = lane >> 4, l16 = lane & 15;

    const int id = blockIdx.x;
    int rt, nt;
    if (id < 576) { rt = (id & 7) + 8 * ((id >> 3) % 6); nt = (id >> 3) / 6; }
    else          { rt = 48; nt = id - 576; }

    const unsigned short* Ab = Hb  + (size_t)rt * 48 * 4096;
    const unsigned short* Bb = W2t + (size_t)nt * 48 * 4096;

    f32x4 acc[2][2] = {};

    auto stage = [&](int i, unsigned short* d) {   // 2 loads/thread (512 thr x 16B = 8KB each)
        gld_lds16(Ab + (size_t)i * 4096 + tid * 8, d + tid * 8);
        gld_lds16(Bb + (size_t)i * 4096 + tid * 8, d + 4096 + tid * 8);
    };

    const int offA = (wm * 32 + l16) * 8;
    const int offB = 4096 + (wn * 32 + l16) * 8;
    const int ko   = (kg * 4 + q) * 512;           // this group's k-half of the atom
    auto compute = [&](const unsigned short* buf) {
        bf16x8 af0 = *(const bf16x8*)(buf + ko + offA);
        bf16x8 af1 = *(const bf16x8*)(buf + ko + offA + 128);
        bf16x8 bf0 = *(const bf16x8*)(buf + ko + offB);
        bf16x8 bf1 = *(const bf16x8*)(buf + ko + offB + 128);
        acc[0][0] = __builtin_amdgcn_mfma_f32_16x16x32_bf16(af0, bf0, acc[0][0], 0, 0, 0);
        acc[0][1] = __builtin_amdgcn_mfma_f32_16x16x32_bf16(af0, bf1, acc[0][1], 0, 0, 0);
        acc[1][0] = __builtin_amdgcn_mfma_f32_16x16x32_bf16(af1, bf0, acc[1][0], 0, 0, 0);
        acc[1][1] = __builtin_amdgcn_mfma_f32_16x16x32_bf16(af1, bf1, acc[1][1], 0, 0, 0);
    };

    unsigned short* s0 = sm;
    unsigned short* s1 = sm + 8192;
    unsigned short* s2 = sm + 16384;

    stage(0, s0);
    stage(1, s1);
    for (int i = 0; i < 48; i += 3) {
        stage(i + 2, s2); WAIT_VM(4);
        BAR(); compute(s0); BAR_LDS();
        if (i + 3 < 48) { stage(i + 3, s0); WAIT_VM(4); } else { WAIT_VM(2); }
        BAR(); compute(s1); BAR_LDS();
        if (i + 4 < 48) { stage(i + 4, s1); WAIT_VM(4); }
        else if (i + 3 < 48) { WAIT_VM(2); }
        else { WAIT_VM(0); }
        BAR(); compute(s2);
        if (i + 3 < 48) BAR_LDS();
    }

    // ---- K-split reduction: kg=1 spills partials to LDS, kg=0 accumulates ----
    float* smf = (float*)sm;
    __syncthreads();                           // all compute done, staging LDS dead
    if (kg == 1) {
        #pragma unroll
        for (int ii = 0; ii < 2; ++ii)
            #pragma unroll
            for (int jj = 0; jj < 2; ++jj)
                *(f32x4*)(smf + ((size_t)((w * 4 + ii * 2 + jj) * 64 + lane)) * 4) = acc[ii][jj];
    }
    __syncthreads();
    if (kg == 1) return;
    #pragma unroll
    for (int ii = 0; ii < 2; ++ii)
        #pragma unroll
        for (int jj = 0; jj < 2; ++jj) {
            f32x4 p = *(const f32x4*)(smf + ((size_t)((w * 4 + ii * 2 + jj) * 64 + lane)) * 4);
            acc[ii][jj] += p;
        }

    // epilogue: C/D col=lane&15, row=(lane>>4)*4+reg; 3136 = 49*64 -> no bounds
    const int row0 = rt * 64 + wm * 32;
    const int col0 = nt * 64 + wn * 32;
    #pragma unroll
    for (int ii = 0; ii < 2; ++ii) {
        #pragma unroll
        for (int jj = 0; jj < 2; ++jj) {
            int col = col0 + jj * 16 + l16;
            float bv = b2[col];
            #pragma unroll
            for (int r = 0; r < 4; ++r) {
                int row = row0 + ii * 16 + q * 4 + r;
                out[(size_t)row * 768 + col] = acc[ii][jj][r] + bv;
            }
        }
    }
}

extern "C" void kernel_launch(void* const* d_in, const int* in_sizes, int n_in,
                              void* d_out, int out_size, void* d_ws, size_t ws_size,
                              hipStream_t stream) {
    const float* slots  = (const float*)d_in[0];   // 16*8*768
    const float* pos    = (const float*)d_in[1];   // 196*768
    // d_in[2] = map_alpha: unused (softmax over K of identical values = 1/K)
    const float* W1     = (const float*)d_in[3];   // 768*3072
    // d_in[4] = b1
    const float* b1     = (const float*)d_in[4];   // 3072
    const float* W2     = (const float*)d_in[5];   // 3072*768
    const float* b2     = (const float*)d_in[6];   // 768
    float* out = (float*)d_out;                    // 3136*768 f32

    size_t off = 0;
    auto alloc = [&](size_t bytes) {
        void* p = (char*)d_ws + off;
        off += (bytes + 255) & ~(size_t)255;
        return p;
    };
    float*          C1  = (float*)alloc((size_t)384 * 3072 * 4);              // row-major
    unsigned short* W2t = (unsigned short*)alloc((size_t)768 * 3072 * 2);     // [12][48] atoms
    unsigned short* Hb  = (unsigned short*)alloc((size_t)49 * 48 * 4096 * 2); // [49][48] atoms

    // 1) GEMM1 frag-direct (288 swizzled tiles) + W2t conversion (288 blocks)
    k_gemm1d<<<576, 256, 0, stream>>>(slots, pos, W1, W2, C1, W2t);
    // 2) hbar -> Hb atoms (4704 blocks)
    k_hbar<<<4704, 256, 0, stream>>>(C1, b1, Hb);
    // 3) out = Hb @ W2t^T + b2 (588 blocks x 512 thr, K-split-2, wave-tile 32x32)
    k_gemm2<<<588, 512, 0, stream>>>(Hb, W2t, b2, out);
}

// Round 6
// 142.774 us; speedup vs baseline: 2.9946x; 1.1267x over previous
//
#include <hip/hip_runtime.h>
#include <hip/hip_bf16.h>
#include <stdint.h>

// B=16, K=8, N=196, D=768, H=3072, DOUT=768
// y[b,n,:] = (mean_k relu(slots[b,k]@W1 + pos[n]@W1 + b1)) @ W2 + b2
// (softmax over K of K-identical values is exactly 1/K; map_alpha unused)
//
// Dispatches:
//  k_prep:      W1->W1t atoms + A1=[slots;pos] atoms (bf16)      [champion]
//  k_gemm1_w2t: C1 = A1 @ W1t^T (288 tiles, XCD nt-swizzle) + W2t [champion]
//  k_hbar:      Hb atoms (49 row-atoms, 4704 blocks)             [champion]
//  k_gemm2:     out = Hb @ W2t^T + b2 — NO-SYNC variant: fragments loaded
//               directly from packed atom images as bf16x8 (quarter-wave
//               256B segments, same coalescing as gld_lds staging; unlike
//               R4's failed k-strided-scalar frag-direct). Zero barriers,
//               zero main-loop LDS -> structurally hang-free (R2/R5 lesson:
//               both container deaths came from novel sync structures).
//               8 waves = 2 K-groups (even/odd atoms) x 4 waves (2x2 of
//               32x32); 4 loads + 4 MFMA per ks-step; rt-XCD partition
//               keeps Hb slice in one XCD L2. K-split LDS-reduce epilogue.
// Accounting (R3/R4): dur_us = sum(kernels) + ~47us harness workspace fill.
// Atom = 64x64 bf16 tile, image [kb 0..7][r 0..63] chunks of 8; off=(kb*64+r)*8.

typedef __attribute__((ext_vector_type(8))) short bf16x8;
typedef __attribute__((ext_vector_type(4))) float f32x4;

#define AS1 __attribute__((address_space(1)))
#define AS3 __attribute__((address_space(3)))

#define WAIT_VM(N) asm volatile("s_waitcnt vmcnt(" #N ")" ::: "memory")
#define BAR()      asm volatile("s_barrier" ::: "memory")
#define BAR_LDS()  asm volatile("s_waitcnt lgkmcnt(0)\ns_barrier" ::: "memory")

static __device__ __forceinline__ void gld_lds16(const void* g, void* l) {
    __builtin_amdgcn_global_load_lds((const AS1 unsigned int*)g,
                                     (AS3 unsigned int*)l, 16, 0, 0);
}

static __device__ __forceinline__ unsigned short f2bf(float f) {
    union { float f; unsigned int u; } v; v.f = f;
    unsigned int u = v.u;
    return (unsigned short)((u + 0x7fffu + ((u >> 16) & 1u)) >> 16);  // RNE
}

// ---------------- prep: W1t tiled transpose + A1 tiled pack ----------------
__global__ void k_prep(const float* __restrict__ W1, unsigned short* __restrict__ W1t,
                       const float* __restrict__ S, const float* __restrict__ P,
                       unsigned short* __restrict__ A1) {
    int idx = blockIdx.x * blockDim.x + threadIdx.x;
    const int C1n = 96 * 3072;          // W1t tasks
    const int PKn = 96 * 384;           // A1 tasks
    if (idx < C1n) {
        int r  = idx % 3072;            // consecutive tid -> consecutive r (coalesced)
        int kc = idx / 3072;            // 8-elem k-chunk (0..95)
        unsigned int po[4];
        #pragma unroll
        for (int j = 0; j < 4; ++j) {
            unsigned short lo = f2bf(W1[(size_t)(kc * 8 + 2 * j) * 3072 + r]);
            unsigned short hi = f2bf(W1[(size_t)(kc * 8 + 2 * j + 1) * 3072 + r]);
            po[j] = (unsigned int)lo | ((unsigned int)hi << 16);
        }
        size_t dst = ((size_t)(r >> 6) * 12 + (kc >> 3)) * 4096
                   + (size_t)((kc & 7) * 64 + (r & 63)) * 8;
        *(uint4*)(W1t + dst) = make_uint4(po[0], po[1], po[2], po[3]);
    } else if (idx < C1n + PKn) {
        int t = idx - C1n;
        int r  = t % 384;
        int kc = t / 384;
        uint4 o = make_uint4(0u, 0u, 0u, 0u);
        if (r < 324) {
            const float* src = (r < 128) ? (S + (size_t)r * 768 + kc * 8)
                                         : (P + (size_t)(r - 128) * 768 + kc * 8);
            float4 a = *(const float4*)(src);
            float4 b = *(const float4*)(src + 4);
            o.x = (unsigned int)f2bf(a.x) | ((unsigned int)f2bf(a.y) << 16);
            o.y = (unsigned int)f2bf(a.z) | ((unsigned int)f2bf(a.w) << 16);
            o.z = (unsigned int)f2bf(b.x) | ((unsigned int)f2bf(b.y) << 16);
            o.w = (unsigned int)f2bf(b.z) | ((unsigned int)f2bf(b.w) << 16);
        }
        size_t dst = ((size_t)(r >> 6) * 12 + (kc >> 3)) * 4096
                   + (size_t)((kc & 7) * 64 + (r & 63)) * 8;
        *(uint4*)(A1 + dst) = o;
    }
}

// ---- GEMM1 (288 tiles, BM=BN=64, 3-stage, XCD nt-swizzle) + W2t (1152 blocks) ----
__launch_bounds__(256)
__global__ void k_gemm1_w2t(const unsigned short* __restrict__ A,
                            const unsigned short* __restrict__ Bt,
                            float* __restrict__ C,
                            const float* __restrict__ W2,
                            unsigned short* __restrict__ W2t) {
    const int tid = threadIdx.x;
    if (blockIdx.x >= 288) {            // ---- W2t conversion ----
        int idx = (blockIdx.x - 288) * 256 + tid;    // 0..294911
        int r  = idx % 768;
        int kc = idx / 768;             // 0..383
        unsigned int po[4];
        #pragma unroll
        for (int j = 0; j < 4; ++j) {
            unsigned short lo = f2bf(W2[(size_t)(kc * 8 + 2 * j) * 768 + r]);
            unsigned short hi = f2bf(W2[(size_t)(kc * 8 + 2 * j + 1) * 768 + r]);
            po[j] = (unsigned int)lo | ((unsigned int)hi << 16);
        }
        size_t dst = ((size_t)(r >> 6) * 48 + (kc >> 3)) * 4096
                   + (size_t)((kc & 7) * 64 + (r & 63)) * 8;
        *(uint4*)(W2t + dst) = make_uint4(po[0], po[1], po[2], po[3]);
        return;
    }

    __shared__ unsigned short sm[3 * 8192];   // 48 KB
    const int lane = tid & 63;
    const int wave = tid >> 6;
    const int wm = wave >> 1, wn = wave & 1;
    const int q = lane >> 4, l16 = lane & 15;

    // swizzle: XCD x = id&7 owns nt in [6x, 6x+6) -> W1t slice L2-resident
    const int id = blockIdx.x;
    const int j  = id >> 3;
    const int nt = (id & 7) * 6 + j % 6;
    const int rt = j / 6;

    const unsigned short* Ab = A  + (size_t)rt * 12 * 4096;
    const unsigned short* Bb = Bt + (size_t)nt * 12 * 4096;

    f32x4 acc[2][2] = {};
    const int offA = (wm * 32 + l16) * 8;
    const int offB = 4096 + (wn * 32 + l16) * 8;

    auto stage = [&](int i, unsigned short* d) {     // 4 loads/thread
        const unsigned short* Ag = Ab + (size_t)i * 4096;
        const unsigned short* Bg = Bb + (size_t)i * 4096;
        gld_lds16(Ag + tid * 8,        d + tid * 8);
        gld_lds16(Ag + 2048 + tid * 8, d + 2048 + tid * 8);
        gld_lds16(Bg + tid * 8,        d + 4096 + tid * 8);
        gld_lds16(Bg + 2048 + tid * 8, d + 6144 + tid * 8);
    };
    auto compute = [&](const unsigned short* buf) {
        #pragma unroll
        for (int ks = 0; ks < 2; ++ks) {
            const int ko = (ks * 4 + q) * 512;
            bf16x8 af0 = *(const bf16x8*)(buf + ko + offA);
            bf16x8 af1 = *(const bf16x8*)(buf + ko + offA + 128);
            bf16x8 bf0 = *(const bf16x8*)(buf + ko + offB);
            bf16x8 bf1 = *(const bf16x8*)(buf + ko + offB + 128);
            acc[0][0] = __builtin_amdgcn_mfma_f32_16x16x32_bf16(af0, bf0, acc[0][0], 0, 0, 0);
            acc[0][1] = __builtin_amdgcn_mfma_f32_16x16x32_bf16(af0, bf1, acc[0][1], 0, 0, 0);
            acc[1][0] = __builtin_amdgcn_mfma_f32_16x16x32_bf16(af1, bf0, acc[1][0], 0, 0, 0);
            acc[1][1] = __builtin_amdgcn_mfma_f32_16x16x32_bf16(af1, bf1, acc[1][1], 0, 0, 0);
        }
    };

    unsigned short* s0 = sm;
    unsigned short* s1 = sm + 8192;
    unsigned short* s2 = sm + 16384;

    stage(0, s0);
    stage(1, s1);
    for (int i = 0; i < 12; i += 3) {
        stage(i + 2, s2); WAIT_VM(8);
        BAR(); compute(s0); BAR_LDS();
        if (i + 3 < 12) { stage(i + 3, s0); WAIT_VM(8); } else { WAIT_VM(4); }
        BAR(); compute(s1); BAR_LDS();
        if (i + 4 < 12) { stage(i + 4, s1); WAIT_VM(8); }
        else if (i + 3 < 12) { WAIT_VM(4); }
        else { WAIT_VM(0); }
        BAR(); compute(s2);
        if (i + 3 < 12) BAR_LDS();
    }

    const int row0 = rt * 64 + wm * 32;
    const int col0 = nt * 64 + wn * 32;
    #pragma unroll
    for (int ii = 0; ii < 2; ++ii) {
        #pragma unroll
        for (int jj = 0; jj < 2; ++jj) {
            int col = col0 + jj * 16 + l16;
            #pragma unroll
            for (int r = 0; r < 4; ++r) {
                int row = row0 + ii * 16 + q * 4 + r;
                if (row < 324) C[(size_t)row * 3072 + col] = acc[ii][jj][r];
            }
        }
    }
}

// ---- hbar: Hb atoms (49 row-atoms), 4704 blocks ----
__global__ void k_hbar(const float* __restrict__ C1, const float* __restrict__ b1,
                       unsigned short* __restrict__ Hb) {
    const int bid  = blockIdx.x;
    const int tid  = threadIdx.x;
    const int bx   = bid % 49;                     // row-atom 0..48
    const int yq   = bid / 49;                     // 0..95
    const int lane = tid & 63;
    const int wv   = tid >> 6;
    const int hc   = yq * 4 + wv;                  // 0..383
    const int h0   = hc * 8;
    const int bn   = bx * 64 + lane;               // 0..3135 (49*64=3136 exact)
    const int b    = bn / 196;
    const int n    = bn - b * 196;
    const float* prow = C1 + (size_t)(128 + n) * 3072 + h0;
    float4 pA = *(const float4*)(prow);
    float4 pB = *(const float4*)(prow + 4);
    float4 bA = *(const float4*)(b1 + h0);
    float4 bB = *(const float4*)(b1 + h0 + 4);
    float pb[8] = { pA.x + bA.x, pA.y + bA.y, pA.z + bA.z, pA.w + bA.w,
                    pB.x + bB.x, pB.y + bB.y, pB.z + bB.z, pB.w + bB.w };
    float acc[8] = {};
    #pragma unroll
    for (int k = 0; k < 8; ++k) {
        const float* srow = C1 + (size_t)(b * 8 + k) * 3072 + h0;  // wave-broadcast-ish
        float4 sA_ = *(const float4*)(srow);
        float4 sB_ = *(const float4*)(srow + 4);
        acc[0] += fmaxf(sA_.x + pb[0], 0.f);
        acc[1] += fmaxf(sA_.y + pb[1], 0.f);
        acc[2] += fmaxf(sA_.z + pb[2], 0.f);
        acc[3] += fmaxf(sA_.w + pb[3], 0.f);
        acc[4] += fmaxf(sB_.x + pb[4], 0.f);
        acc[5] += fmaxf(sB_.y + pb[5], 0.f);
        acc[6] += fmaxf(sB_.z + pb[6], 0.f);
        acc[7] += fmaxf(sB_.w + pb[7], 0.f);
    }
    unsigned int w0 = (unsigned int)f2bf(acc[0] * 0.125f) | ((unsigned int)f2bf(acc[1] * 0.125f) << 16);
    unsigned int w1 = (unsigned int)f2bf(acc[2] * 0.125f) | ((unsigned int)f2bf(acc[3] * 0.125f) << 16);
    unsigned int w2 = (unsigned int)f2bf(acc[4] * 0.125f) | ((unsigned int)f2bf(acc[5] * 0.125f) << 16);
    unsigned int w3 = (unsigned int)f2bf(acc[6] * 0.125f) | ((unsigned int)f2bf(acc[7] * 0.125f) << 16);
    size_t dst = ((size_t)bx * 48 + (hc >> 3)) * 4096
               + (size_t)((hc & 7) * 64 + lane) * 8;
    *(uint4*)(Hb + dst) = make_uint4(w0, w1, w2, w3);
}

// ---- GEMM2 (no-LDS-staging, no-barrier): out = Hb @ W2t^T + b2 ----
// 588 blocks (49 rt x 12 nt), rt-XCD partition: rt=(id&7)+8*((id>>3)%6), tail rt=48.
// Hb atoms [49][48][4096]; W2t atoms [12][48][4096]; out 3136x768 f32 + b2.
// Fragment (k-chunk kb, col c) of atom a = 16B at a*4096 + (kb*64+c)*8 ->
// direct bf16x8 loads, 16 l16-lanes = 256B contiguous. kg=wave>>2 takes
// even (kg=0) / odd (kg=1) atoms; per ks-step 4 loads + 4 MFMA; no sync.
__launch_bounds__(512)
__global__ void k_gemm2(const unsigned short* __restrict__ Hb,
                        const unsigned short* __restrict__ W2t,
                        const float* __restrict__ b2, float* __restrict__ out) {
    __shared__ float smf[4096];                // 16 KB reduction buffer only

    const int tid  = threadIdx.x;              // 0..511
    const int lane = tid & 63;
    const int wave = tid >> 6;                 // 0..7
    const int kg = wave >> 2;                  // K-group 0/1 (even/odd atoms)
    const int w  = wave & 3;                   // wave-in-group
    const int wm = w >> 1, wn = w & 1;         // 2 x 2 wave grid, tile 32x32
    const int q = lane >> 4, l16 = lane & 15;

    const int id = blockIdx.x;
    int rt, nt;
    if (id < 576) { rt = (id & 7) + 8 * ((id >> 3) % 6); nt = (id >> 3) / 6; }
    else          { rt = 48; nt = id - 576; }

    // per-wave fragment stream bases (atom parity kg, k-chunk q, rows/cols)
    const unsigned short* Aw = Hb  + (size_t)rt * 48 * 4096
                             + (size_t)kg * 4096 + q * 512 + (wm * 32 + l16) * 8;
    const unsigned short* Bw = W2t + (size_t)nt * 48 * 4096
                             + (size_t)kg * 4096 + q * 512 + (wn * 32 + l16) * 8;

    f32x4 acc[2][2] = {};
    #pragma unroll 4
    for (int p = 0; p < 24; ++p) {             // atom pair p: this wave takes 2p+kg
        const size_t base = (size_t)p * 8192;
        #pragma unroll
        for (int ks = 0; ks < 2; ++ks) {       // k-chunk kb = ks*4 + q
            const size_t o = base + ks * 2048;
            bf16x8 af0 = *(const bf16x8*)(Aw + o);
            bf16x8 af1 = *(const bf16x8*)(Aw + o + 128);
            bf16x8 bf0 = *(const bf16x8*)(Bw + o);
            bf16x8 bf1 = *(const bf16x8*)(Bw + o + 128);
            acc[0][0] = __builtin_amdgcn_mfma_f32_16x16x32_bf16(af0, bf0, acc[0][0], 0, 0, 0);
            acc[0][1] = __builtin_amdgcn_mfma_f32_16x16x32_bf16(af0, bf1, acc[0][1], 0, 0, 0);
            acc[1][0] = __builtin_amdgcn_mfma_f32_16x16x32_bf16(af1, bf0, acc[1][0], 0, 0, 0);
            acc[1][1] = __builtin_amdgcn_mfma_f32_16x16x32_bf16(af1, bf1, acc[1][1], 0, 0, 0);
        }
    }

    // ---- K-split reduction: kg=1 spills partials to LDS, kg=0 accumulates ----
    __syncthreads();
    if (kg == 1) {
        #pragma unroll
        for (int ii = 0; ii < 2; ++ii)
            #pragma unroll
            for (int jj = 0; jj < 2; ++jj)
                *(f32x4*)(smf + ((size_t)((w * 4 + ii * 2 + jj) * 64 + lane)) * 4) = acc[ii][jj];
    }
    __syncthreads();
    if (kg == 1) return;
    #pragma unroll
    for (int ii = 0; ii < 2; ++ii)
        #pragma unroll
        for (int jj = 0; jj < 2; ++jj) {
            f32x4 p = *(const f32x4*)(smf + ((size_t)((w * 4 + ii * 2 + jj) * 64 + lane)) * 4);
            acc[ii][jj] += p;
        }

    // epilogue: C/D col=lane&15, row=(lane>>4)*4+reg; 3136 = 49*64 -> no bounds
    const int row0 = rt * 64 + wm * 32;
    const int col0 = nt * 64 + wn * 32;
    #pragma unroll
    for (int ii = 0; ii < 2; ++ii) {
        #pragma unroll
        for (int jj = 0; jj < 2; ++jj) {
            int col = col0 + jj * 16 + l16;
            float bv = b2[col];
            #pragma unroll
            for (int r = 0; r < 4; ++r) {
                int row = row0 + ii * 16 + q * 4 + r;
                out[(size_t)row * 768 + col] = acc[ii][jj][r] + bv;
            }
        }
    }
}

extern "C" void kernel_launch(void* const* d_in, const int* in_sizes, int n_in,
                              void* d_out, int out_size, void* d_ws, size_t ws_size,
                              hipStream_t stream) {
    const float* slots  = (const float*)d_in[0];   // 16*8*768
    const float* pos    = (const float*)d_in[1];   // 196*768
    // d_in[2] = map_alpha: unused (softmax over K of identical values = 1/K)
    const float* W1     = (const float*)d_in[3];   // 768*3072
    const float* b1     = (const float*)d_in[4];   // 3072
    const float* W2     = (const float*)d_in[5];   // 3072*768
    const float* b2     = (const float*)d_in[6];   // 768
    float* out = (float*)d_out;                    // 3136*768 f32

    size_t off = 0;
    auto alloc = [&](size_t bytes) {
        void* p = (char*)d_ws + off;
        off += (bytes + 255) & ~(size_t)255;
        return p;
    };
    unsigned short* W1t = (unsigned short*)alloc((size_t)3072 * 768 * 2);     // [48][12] atoms
    unsigned short* W2t = (unsigned short*)alloc((size_t)768 * 3072 * 2);     // [12][48] atoms
    unsigned short* A1  = (unsigned short*)alloc((size_t)384 * 768 * 2);      // [6][12] atoms
    float*          C1  = (float*)alloc((size_t)384 * 3072 * 4);              // row-major
    unsigned short* Hb  = (unsigned short*)alloc((size_t)49 * 48 * 4096 * 2); // [49][48] atoms

    // 1) prep: W1t + A1 (331776 tasks, 1296 blocks)
    k_prep<<<1296, 256, 0, stream>>>(W1, W1t, slots, pos, A1);
    // 2) GEMM1 (288 swizzled tiles) + W2t conversion (1152 blocks)
    k_gemm1_w2t<<<1440, 256, 0, stream>>>(A1, W1t, C1, W2, W2t);
    // 3) hbar -> Hb atoms (4704 blocks)
    k_hbar<<<4704, 256, 0, stream>>>(C1, b1, Hb);
    // 4) out = Hb @ W2t^T + b2 (588 blocks x 512 thr, no-sync frag-direct)
    k_gemm2<<<588, 512, 0, stream>>>(Hb, W2t, b2, out);
}

// Round 7
// 131.989 us; speedup vs baseline: 3.2393x; 1.0817x over previous
//
#include <hip/hip_runtime.h>
#include <hip/hip_bf16.h>
#include <stdint.h>

// B=16, K=8, N=196, D=768, H=3072, DOUT=768
// y[b,n,:] = (mean_k relu(slots[b,k]@W1 + pos[n]@W1 + b1)) @ W2 + b2
// (softmax over K of K-identical values is exactly 1/K; map_alpha unused)
//
// Dispatches:
//  k_prep:      W1->W1t atoms + A1=[slots;pos] atoms (bf16)      [champion]
//  k_gemm1_w2t: C1 = A1 @ W1t^T (288 tiles, XCD nt-swizzle) + W2t [champion]
//  k_hbar:      Hb atoms (49 row-atoms, 4704 blocks)             [champion]
//  k_gemm2:     out = Hb @ W2t^T + b2. R6 evidence: no-sync frag-direct was
//               +13.8us (L2 re-reads + raw latency) and R1 showed LDS-read
//               volume is not the limit -> the drain STRUCTURE is. New loop:
//               4-buffer (64 KB) lookahead-3, ONE s_barrier + one counted
//               vmcnt per atom, order {WAIT_VM; BAR; stage(t+3); compute(t)}.
//               Passing BAR at t implies all waves finished compute(t-1), so
//               stage(t+3) overwriting buf[(t-1)&3] is race-free. vmcnt
//               ledger: entry outstanding 2*min(3,48-t) -> wait 4/4/2/0;
//               never a mid-loop full drain, no per-step lgkm drain.
//               K-split wave layout + LDS-reduce epilogue = R1 proven code.
// Accounting (R3/R4): dur_us = sum(kernels) + ~47us harness workspace fill.
// Atom = 64x64 bf16 tile, image [kb 0..7][r 0..63] chunks of 8; off=(kb*64+r)*8.

typedef __attribute__((ext_vector_type(8))) short bf16x8;
typedef __attribute__((ext_vector_type(4))) float f32x4;

#define AS1 __attribute__((address_space(1)))
#define AS3 __attribute__((address_space(3)))

#define WAIT_VM(N) asm volatile("s_waitcnt vmcnt(" #N ")" ::: "memory")
#define BAR()      asm volatile("s_barrier" ::: "memory")
#define BAR_LDS()  asm volatile("s_waitcnt lgkmcnt(0)\ns_barrier" ::: "memory")

static __device__ __forceinline__ void gld_lds16(const void* g, void* l) {
    __builtin_amdgcn_global_load_lds((const AS1 unsigned int*)g,
                                     (AS3 unsigned int*)l, 16, 0, 0);
}

static __device__ __forceinline__ unsigned short f2bf(float f) {
    union { float f; unsigned int u; } v; v.f = f;
    unsigned int u = v.u;
    return (unsigned short)((u + 0x7fffu + ((u >> 16) & 1u)) >> 16);  // RNE
}

// ---------------- prep: W1t tiled transpose + A1 tiled pack ----------------
__global__ void k_prep(const float* __restrict__ W1, unsigned short* __restrict__ W1t,
                       const float* __restrict__ S, const float* __restrict__ P,
                       unsigned short* __restrict__ A1) {
    int idx = blockIdx.x * blockDim.x + threadIdx.x;
    const int C1n = 96 * 3072;          // W1t tasks
    const int PKn = 96 * 384;           // A1 tasks
    if (idx < C1n) {
        int r  = idx % 3072;            // consecutive tid -> consecutive r (coalesced)
        int kc = idx / 3072;            // 8-elem k-chunk (0..95)
        unsigned int po[4];
        #pragma unroll
        for (int j = 0; j < 4; ++j) {
            unsigned short lo = f2bf(W1[(size_t)(kc * 8 + 2 * j) * 3072 + r]);
            unsigned short hi = f2bf(W1[(size_t)(kc * 8 + 2 * j + 1) * 3072 + r]);
            po[j] = (unsigned int)lo | ((unsigned int)hi << 16);
        }
        size_t dst = ((size_t)(r >> 6) * 12 + (kc >> 3)) * 4096
                   + (size_t)((kc & 7) * 64 + (r & 63)) * 8;
        *(uint4*)(W1t + dst) = make_uint4(po[0], po[1], po[2], po[3]);
    } else if (idx < C1n + PKn) {
        int t = idx - C1n;
        int r  = t % 384;
        int kc = t / 384;
        uint4 o = make_uint4(0u, 0u, 0u, 0u);
        if (r < 324) {
            const float* src = (r < 128) ? (S + (size_t)r * 768 + kc * 8)
                                         : (P + (size_t)(r - 128) * 768 + kc * 8);
            float4 a = *(const float4*)(src);
            float4 b = *(const float4*)(src + 4);
            o.x = (unsigned int)f2bf(a.x) | ((unsigned int)f2bf(a.y) << 16);
            o.y = (unsigned int)f2bf(a.z) | ((unsigned int)f2bf(a.w) << 16);
            o.z = (unsigned int)f2bf(b.x) | ((unsigned int)f2bf(b.y) << 16);
            o.w = (unsigned int)f2bf(b.z) | ((unsigned int)f2bf(b.w) << 16);
        }
        size_t dst = ((size_t)(r >> 6) * 12 + (kc >> 3)) * 4096
                   + (size_t)((kc & 7) * 64 + (r & 63)) * 8;
        *(uint4*)(A1 + dst) = o;
    }
}

// ---- GEMM1 (288 tiles, BM=BN=64, 3-stage, XCD nt-swizzle) + W2t (1152 blocks) ----
__launch_bounds__(256)
__global__ void k_gemm1_w2t(const unsigned short* __restrict__ A,
                            const unsigned short* __restrict__ Bt,
                            float* __restrict__ C,
                            const float* __restrict__ W2,
                            unsigned short* __restrict__ W2t) {
    const int tid = threadIdx.x;
    if (blockIdx.x >= 288) {            // ---- W2t conversion ----
        int idx = (blockIdx.x - 288) * 256 + tid;    // 0..294911
        int r  = idx % 768;
        int kc = idx / 768;             // 0..383
        unsigned int po[4];
        #pragma unroll
        for (int j = 0; j < 4; ++j) {
            unsigned short lo = f2bf(W2[(size_t)(kc * 8 + 2 * j) * 768 + r]);
            unsigned short hi = f2bf(W2[(size_t)(kc * 8 + 2 * j + 1) * 768 + r]);
            po[j] = (unsigned int)lo | ((unsigned int)hi << 16);
        }
        size_t dst = ((size_t)(r >> 6) * 48 + (kc >> 3)) * 4096
                   + (size_t)((kc & 7) * 64 + (r & 63)) * 8;
        *(uint4*)(W2t + dst) = make_uint4(po[0], po[1], po[2], po[3]);
        return;
    }

    __shared__ unsigned short sm[3 * 8192];   // 48 KB
    const int lane = tid & 63;
    const int wave = tid >> 6;
    const int wm = wave >> 1, wn = wave & 1;
    const int q = lane >> 4, l16 = lane & 15;

    // swizzle: XCD x = id&7 owns nt in [6x, 6x+6) -> W1t slice L2-resident
    const int id = blockIdx.x;
    const int j  = id >> 3;
    const int nt = (id & 7) * 6 + j % 6;
    const int rt = j / 6;

    const unsigned short* Ab = A  + (size_t)rt * 12 * 4096;
    const unsigned short* Bb = Bt + (size_t)nt * 12 * 4096;

    f32x4 acc[2][2] = {};
    const int offA = (wm * 32 + l16) * 8;
    const int offB = 4096 + (wn * 32 + l16) * 8;

    auto stage = [&](int i, unsigned short* d) {     // 4 loads/thread
        const unsigned short* Ag = Ab + (size_t)i * 4096;
        const unsigned short* Bg = Bb + (size_t)i * 4096;
        gld_lds16(Ag + tid * 8,        d + tid * 8);
        gld_lds16(Ag + 2048 + tid * 8, d + 2048 + tid * 8);
        gld_lds16(Bg + tid * 8,        d + 4096 + tid * 8);
        gld_lds16(Bg + 2048 + tid * 8, d + 6144 + tid * 8);
    };
    auto compute = [&](const unsigned short* buf) {
        #pragma unroll
        for (int ks = 0; ks < 2; ++ks) {
            const int ko = (ks * 4 + q) * 512;
            bf16x8 af0 = *(const bf16x8*)(buf + ko + offA);
            bf16x8 af1 = *(const bf16x8*)(buf + ko + offA + 128);
            bf16x8 bf0 = *(const bf16x8*)(buf + ko + offB);
            bf16x8 bf1 = *(const bf16x8*)(buf + ko + offB + 128);
            acc[0][0] = __builtin_amdgcn_mfma_f32_16x16x32_bf16(af0, bf0, acc[0][0], 0, 0, 0);
            acc[0][1] = __builtin_amdgcn_mfma_f32_16x16x32_bf16(af0, bf1, acc[0][1], 0, 0, 0);
            acc[1][0] = __builtin_amdgcn_mfma_f32_16x16x32_bf16(af1, bf0, acc[1][0], 0, 0, 0);
            acc[1][1] = __builtin_amdgcn_mfma_f32_16x16x32_bf16(af1, bf1, acc[1][1], 0, 0, 0);
        }
    };

    unsigned short* s0 = sm;
    unsigned short* s1 = sm + 8192;
    unsigned short* s2 = sm + 16384;

    stage(0, s0);
    stage(1, s1);
    for (int i = 0; i < 12; i += 3) {
        stage(i + 2, s2); WAIT_VM(8);
        BAR(); compute(s0); BAR_LDS();
        if (i + 3 < 12) { stage(i + 3, s0); WAIT_VM(8); } else { WAIT_VM(4); }
        BAR(); compute(s1); BAR_LDS();
        if (i + 4 < 12) { stage(i + 4, s1); WAIT_VM(8); }
        else if (i + 3 < 12) { WAIT_VM(4); }
        else { WAIT_VM(0); }
        BAR(); compute(s2);
        if (i + 3 < 12) BAR_LDS();
    }

    const int row0 = rt * 64 + wm * 32;
    const int col0 = nt * 64 + wn * 32;
    #pragma unroll
    for (int ii = 0; ii < 2; ++ii) {
        #pragma unroll
        for (int jj = 0; jj < 2; ++jj) {
            int col = col0 + jj * 16 + l16;
            #pragma unroll
            for (int r = 0; r < 4; ++r) {
                int row = row0 + ii * 16 + q * 4 + r;
                if (row < 324) C[(size_t)row * 3072 + col] = acc[ii][jj][r];
            }
        }
    }
}

// ---- hbar: Hb atoms (49 row-atoms), 4704 blocks ----
__global__ void k_hbar(const float* __restrict__ C1, const float* __restrict__ b1,
                       unsigned short* __restrict__ Hb) {
    const int bid  = blockIdx.x;
    const int tid  = threadIdx.x;
    const int bx   = bid % 49;                     // row-atom 0..48
    const int yq   = bid / 49;                     // 0..95
    const int lane = tid & 63;
    const int wv   = tid >> 6;
    const int hc   = yq * 4 + wv;                  // 0..383
    const int h0   = hc * 8;
    const int bn   = bx * 64 + lane;               // 0..3135 (49*64=3136 exact)
    const int b    = bn / 196;
    const int n    = bn - b * 196;
    const float* prow = C1 + (size_t)(128 + n) * 3072 + h0;
    float4 pA = *(const float4*)(prow);
    float4 pB = *(const float4*)(prow + 4);
    float4 bA = *(const float4*)(b1 + h0);
    float4 bB = *(const float4*)(b1 + h0 + 4);
    float pb[8] = { pA.x + bA.x, pA.y + bA.y, pA.z + bA.z, pA.w + bA.w,
                    pB.x + bB.x, pB.y + bB.y, pB.z + bB.z, pB.w + bB.w };
    float acc[8] = {};
    #pragma unroll
    for (int k = 0; k < 8; ++k) {
        const float* srow = C1 + (size_t)(b * 8 + k) * 3072 + h0;  // wave-broadcast-ish
        float4 sA_ = *(const float4*)(srow);
        float4 sB_ = *(const float4*)(srow + 4);
        acc[0] += fmaxf(sA_.x + pb[0], 0.f);
        acc[1] += fmaxf(sA_.y + pb[1], 0.f);
        acc[2] += fmaxf(sA_.z + pb[2], 0.f);
        acc[3] += fmaxf(sA_.w + pb[3], 0.f);
        acc[4] += fmaxf(sB_.x + pb[4], 0.f);
        acc[5] += fmaxf(sB_.y + pb[5], 0.f);
        acc[6] += fmaxf(sB_.z + pb[6], 0.f);
        acc[7] += fmaxf(sB_.w + pb[7], 0.f);
    }
    unsigned int w0 = (unsigned int)f2bf(acc[0] * 0.125f) | ((unsigned int)f2bf(acc[1] * 0.125f) << 16);
    unsigned int w1 = (unsigned int)f2bf(acc[2] * 0.125f) | ((unsigned int)f2bf(acc[3] * 0.125f) << 16);
    unsigned int w2 = (unsigned int)f2bf(acc[4] * 0.125f) | ((unsigned int)f2bf(acc[5] * 0.125f) << 16);
    unsigned int w3 = (unsigned int)f2bf(acc[6] * 0.125f) | ((unsigned int)f2bf(acc[7] * 0.125f) << 16);
    size_t dst = ((size_t)bx * 48 + (hc >> 3)) * 4096
               + (size_t)((hc & 7) * 64 + lane) * 8;
    *(uint4*)(Hb + dst) = make_uint4(w0, w1, w2, w3);
}

// ---- GEMM2: BM=BN=64, 512 thr, K-split-2, 4-buffer lookahead-3 pipeline ----
// 588 blocks (49 rt x 12 nt), rt-XCD partition: rt=(id&7)+8*((id>>3)%6), tail rt=48.
// Hb atoms [49][48][4096]; W2t atoms [12][48][4096]; out 3136x768 f32 + b2.
// Per atom t: {WAIT_VM(counted); BAR; stage(t+3); compute(t)} — ONE barrier,
// no per-step lgkm drain. 64 KB LDS (2 blocks/CU, 16 waves/CU).
__launch_bounds__(512)
__global__ void k_gemm2(const unsigned short* __restrict__ Hb,
                        const unsigned short* __restrict__ W2t,
                        const float* __restrict__ b2, float* __restrict__ out) {
    __shared__ unsigned short sm[4 * 8192];    // 64 KB: 4 buffers x [A 4096 | B 4096 elems]

    const int tid  = threadIdx.x;              // 0..511
    const int lane = tid & 63;
    const int wave = tid >> 6;                 // 0..7
    const int kg = wave >> 2;                  // K-group 0/1
    const int w  = wave & 3;                   // wave-in-group
    const int wm = w >> 1, wn = w & 1;         // 2 x 2 wave grid, tile 32x32
    const int q = lane >> 4, l16 = lane & 15;

    const int id = blockIdx.x;
    int rt, nt;
    if (id < 576) { rt = (id & 7) + 8 * ((id >> 3) % 6); nt = (id >> 3) / 6; }
    else          { rt = 48; nt = id - 576; }

    const unsigned short* Ab = Hb  + (size_t)rt * 48 * 4096;
    const unsigned short* Bb = W2t + (size_t)nt * 48 * 4096;

    f32x4 acc[2][2] = {};

    auto stage = [&](int i) {                  // 2 loads/thread (512 thr x 16B = 8KB each)
        unsigned short* d = sm + (size_t)(i & 3) * 8192;
        gld_lds16(Ab + (size_t)i * 4096 + tid * 8, d + tid * 8);
        gld_lds16(Bb + (size_t)i * 4096 + tid * 8, d + 4096 + tid * 8);
    };

    const int offA = (wm * 32 + l16) * 8;
    const int offB = 4096 + (wn * 32 + l16) * 8;
    const int ko   = (kg * 4 + q) * 512;       // this group's k-half of the atom
    auto compute = [&](const unsigned short* buf) {
        bf16x8 af0 = *(const bf16x8*)(buf + ko + offA);
        bf16x8 af1 = *(const bf16x8*)(buf + ko + offA + 128);
        bf16x8 bf0 = *(const bf16x8*)(buf + ko + offB);
        bf16x8 bf1 = *(const bf16x8*)(buf + ko + offB + 128);
        acc[0][0] = __builtin_amdgcn_mfma_f32_16x16x32_bf16(af0, bf0, acc[0][0], 0, 0, 0);
        acc[0][1] = __builtin_amdgcn_mfma_f32_16x16x32_bf16(af0, bf1, acc[0][1], 0, 0, 0);
        acc[1][0] = __builtin_amdgcn_mfma_f32_16x16x32_bf16(af1, bf0, acc[1][0], 0, 0, 0);
        acc[1][1] = __builtin_amdgcn_mfma_f32_16x16x32_bf16(af1, bf1, acc[1][1], 0, 0, 0);
    };

    stage(0); stage(1); stage(2);              // 6 loads in flight
    #pragma unroll 1
    for (int t = 0; t < 48; ++t) {
        // entry outstanding = 2*min(3, 48-t); complete t's 2 loads:
        if      (t <= 45) { WAIT_VM(4); }
        else if (t == 46) { WAIT_VM(2); }
        else              { WAIT_VM(0); }
        BAR();                                 // all waves: buf[t] ready, compute(t-1) done
        if (t + 3 < 48) stage(t + 3);          // overwrites buf[(t-1)&3] — safe past BAR
        compute(sm + (size_t)(t & 3) * 8192);
    }

    // ---- K-split reduction: kg=1 spills partials to LDS, kg=0 accumulates ----
    float* smf = (float*)sm;
    __syncthreads();                           // all compute done, staging LDS dead
    if (kg == 1) {
        #pragma unroll
        for (int ii = 0; ii < 2; ++ii)
            #pragma unroll
            for (int jj = 0; jj < 2; ++jj)
                *(f32x4*)(smf + ((size_t)((w * 4 + ii * 2 + jj) * 64 + lane)) * 4) = acc[ii][jj];
    }
    __syncthreads();
    if (kg == 1) return;
    #pragma unroll
    for (int ii = 0; ii < 2; ++ii)
        #pragma unroll
        for (int jj = 0; jj < 2; ++jj) {
            f32x4 p = *(const f32x4*)(smf + ((size_t)((w * 4 + ii * 2 + jj) * 64 + lane)) * 4);
            acc[ii][jj] += p;
        }

    // epilogue: C/D col=lane&15, row=(lane>>4)*4+reg; 3136 = 49*64 -> no bounds
    const int row0 = rt * 64 + wm * 32;
    const int col0 = nt * 64 + wn * 32;
    #pragma unroll
    for (int ii = 0; ii < 2; ++ii) {
        #pragma unroll
        for (int jj = 0; jj < 2; ++jj) {
            int col = col0 + jj * 16 + l16;
            float bv = b2[col];
            #pragma unroll
            for (int r = 0; r < 4; ++r) {
                int row = row0 + ii * 16 + q * 4 + r;
                out[(size_t)row * 768 + col] = acc[ii][jj][r] + bv;
            }
        }
    }
}

extern "C" void kernel_launch(void* const* d_in, const int* in_sizes, int n_in,
                              void* d_out, int out_size, void* d_ws, size_t ws_size,
                              hipStream_t stream) {
    const float* slots  = (const float*)d_in[0];   // 16*8*768
    const float* pos    = (const float*)d_in[1];   // 196*768
    // d_in[2] = map_alpha: unused (softmax over K of identical values = 1/K)
    const float* W1     = (const float*)d_in[3];   // 768*3072
    const float* b1     = (const float*)d_in[4];   // 3072
    const float* W2     = (const float*)d_in[5];   // 3072*768
    const float* b2     = (const float*)d_in[6];   // 768
    float* out = (float*)d_out;                    // 3136*768 f32

    size_t off = 0;
    auto alloc = [&](size_t bytes) {
        void* p = (char*)d_ws + off;
        off += (bytes + 255) & ~(size_t)255;
        return p;
    };
    unsigned short* W1t = (unsigned short*)alloc((size_t)3072 * 768 * 2);     // [48][12] atoms
    unsigned short* W2t = (unsigned short*)alloc((size_t)768 * 3072 * 2);     // [12][48] atoms
    unsigned short* A1  = (unsigned short*)alloc((size_t)384 * 768 * 2);      // [6][12] atoms
    float*          C1  = (float*)alloc((size_t)384 * 3072 * 4);              // row-major
    unsigned short* Hb  = (unsigned short*)alloc((size_t)49 * 48 * 4096 * 2); // [49][48] atoms

    // 1) prep: W1t + A1 (331776 tasks, 1296 blocks)
    k_prep<<<1296, 256, 0, stream>>>(W1, W1t, slots, pos, A1);
    // 2) GEMM1 (288 swizzled tiles) + W2t conversion (1152 blocks)
    k_gemm1_w2t<<<1440, 256, 0, stream>>>(A1, W1t, C1, W2, W2t);
    // 3) hbar -> Hb atoms (4704 blocks)
    k_hbar<<<4704, 256, 0, stream>>>(C1, b1, Hb);
    // 4) out = Hb @ W2t^T + b2 (588 blocks x 512 thr, 1-barrier 4-buffer pipeline)
    k_gemm2<<<588, 512, 0, stream>>>(Hb, W2t, b2, out);
}